// Round 1
// baseline (2322.938 us; speedup 1.0000x reference)
//
#include <hip/hip_runtime.h>
#include <math.h>

#define SD 10
#define MD 9

// ---------------- constant gh precompute (h0 is batch-constant) ----------------
// ghQ[j]  = Q_bhh[j] + sum_i Q_Whh[j,11i]      (h_Q0 = eye(10).ravel)
// ghR[j]  = R_bhh[j] + sum_i R_Whh[j,10i]      (h_R0 = eye(9).ravel)
// ghS[j]  = S_bhh[j] + sum_i S_Whh[j,10i]      (h_S0 = eye(9).ravel)
// ghSig   = Sig_bhh directly (h_Sig0 = 0) -> no buffer needed
__global__ void gh_precompute(const float* __restrict__ Q_Whh, const float* __restrict__ Q_bhh,
                              const float* __restrict__ R_Whh, const float* __restrict__ R_bhh,
                              const float* __restrict__ S_Whh, const float* __restrict__ S_bhh,
                              float* __restrict__ gh) {
    int j = threadIdx.x;
    if (j < 300) {
        float s = Q_bhh[j];
        #pragma unroll
        for (int i = 0; i < 10; ++i) s += Q_Whh[j * 100 + 11 * i];
        gh[j] = s;
    }
    if (j < 243) {
        float s = R_bhh[j];
        #pragma unroll
        for (int i = 0; i < 9; ++i) s += R_Whh[j * 81 + 10 * i];
        gh[320 + j] = s;
        float s2 = S_bhh[j];
        #pragma unroll
        for (int i = 0; i < 9; ++i) s2 += S_Whh[j * 81 + 10 * i];
        gh[576 + j] = s2;
    }
}

// ---------------- generic small FC: out = act(scale * (x @ W^T) + b) ----------------
// 32 rows/block staged in LDS; optional L2-normalization folded in as row scale.
__global__ __launch_bounds__(256) void fc_kernel(
    const float* __restrict__ in, int in_ld, int in_off, int K,
    const float* __restrict__ W, const float* __restrict__ bias, int N,
    int do_relu, int do_norm,
    float* __restrict__ dst, int dld, int doff) {
    __shared__ float sIn[32 * 208];
    __shared__ float sScale[32];
    const int tid = threadIdx.x;
    const int row0 = blockIdx.x * 32;
    const int KP = (K & 1) ? K : K + 1;   // odd stride -> conflict-free LDS

    for (int idx = tid; idx < 32 * K; idx += 256) {
        int r = idx / K, k = idx - r * K;
        sIn[r * KP + k] = in[(size_t)(row0 + r) * in_ld + in_off + k];
    }
    __syncthreads();
    if (do_norm) {
        if (tid < 32) {
            float s = 0.f;
            for (int k = 0; k < K; ++k) { float v = sIn[tid * KP + k]; s += v * v; }
            sScale[tid] = 1.0f / fmaxf(sqrtf(s), 1e-12f);
        }
        __syncthreads();
    }
    for (int idx = tid; idx < 32 * N; idx += 256) {
        int r = idx & 31, n = idx >> 5;   // lanes -> consecutive rows, same n (W broadcast)
        float acc = 0.f;
        int k = 0;
        for (; k + 4 <= K; k += 4) {
            acc += sIn[r * KP + k]     * W[n * K + k];
            acc += sIn[r * KP + k + 1] * W[n * K + k + 1];
            acc += sIn[r * KP + k + 2] * W[n * K + k + 2];
            acc += sIn[r * KP + k + 3] * W[n * K + k + 3];
        }
        for (; k < K; ++k) acc += sIn[r * KP + k] * W[n * K + k];
        if (do_norm) acc *= sScale[r];
        acc += bias[n];
        if (do_relu) acc = fmaxf(acc, 0.f);
        dst[(size_t)(row0 + r) * dld + doff + n] = acc;
    }
}

// ---------------- GRU with constant hidden: gi = x@Wih^T + bih, then gates ----------------
__global__ __launch_bounds__(256) void gru_kernel(
    const float* __restrict__ in, int K,             // contiguous [B,K]
    const float* __restrict__ Wih, const float* __restrict__ bih,
    const float* __restrict__ gh, int H, int h0p,    // h0[h] = (h0p>0 && h%h0p==0)
    float* __restrict__ d0, int ld0, int o0,
    float* __restrict__ d1, int ld1, int o1,
    float* __restrict__ d2, int ld2, int o2) {
    __shared__ float sIn[32 * 208];
    __shared__ float sGi[32 * 301];
    const int tid = threadIdx.x;
    const int row0 = blockIdx.x * 32;
    const int KP = (K & 1) ? K : K + 1;
    const int N = 3 * H;
    const int GP = (N & 1) ? N : N + 1;

    for (int idx = tid; idx < 32 * K; idx += 256) {
        int r = idx / K, k = idx - r * K;
        sIn[r * KP + k] = in[(size_t)row0 * K + idx];
    }
    __syncthreads();
    for (int idx = tid; idx < 32 * N; idx += 256) {
        int r = idx & 31, n = idx >> 5;
        float acc = bih[n];
        int k = 0;
        for (; k + 4 <= K; k += 4) {
            acc += sIn[r * KP + k]     * Wih[n * K + k];
            acc += sIn[r * KP + k + 1] * Wih[n * K + k + 1];
            acc += sIn[r * KP + k + 2] * Wih[n * K + k + 2];
            acc += sIn[r * KP + k + 3] * Wih[n * K + k + 3];
        }
        for (; k < K; ++k) acc += sIn[r * KP + k] * Wih[n * K + k];
        sGi[r * GP + n] = acc;
    }
    __syncthreads();
    for (int idx = tid; idx < 32 * H; idx += 256) {
        int r = idx & 31, h = idx >> 5;
        float ir = sGi[r * GP + h];
        float iz = sGi[r * GP + H + h];
        float inn = sGi[r * GP + 2 * H + h];
        float rr = 1.f / (1.f + expf(-(ir + gh[h])));
        float zz = 1.f / (1.f + expf(-(iz + gh[H + h])));
        float nn = tanhf(inn + rr * gh[2 * H + h]);
        float h0 = (h0p > 0 && (h % h0p) == 0) ? 1.f : 0.f;
        float v = (1.f - zz) * nn + zz * h0;
        size_t rw = (size_t)(row0 + r);
        d0[rw * ld0 + o0 + h] = v;
        if (d1) d1[rw * ld1 + o1 + h] = v;
        if (d2) d2[rw * ld2 + o2 + h] = v;
    }
}

// ---------------- fused FC2: out90 = (relu(x@W1^T + b1)) @ W2^T, chunked through LDS ----------------
// grid = (B/32) * 2 : N=7240 split in halves, partial sums combined later.
__global__ __launch_bounds__(256) void fc2_fused(
    const float* __restrict__ in,   // [B,181]
    const float* __restrict__ W1,   // [7240,181]
    const float* __restrict__ b1,   // [7240]
    const float* __restrict__ W2,   // [90,7240]
    float* __restrict__ partial, int B) {
    __shared__ float sIn[32 * 181];
    __shared__ __align__(16) float sW1[64 * 184];   // padded stride -> aligned float4 rows
    __shared__ float sHid[32 * 65];
    const int tid = threadIdx.x;
    const int MB = B / 32;
    const int mtile = blockIdx.x % MB;
    const int half = blockIdx.x / MB;
    const int row0 = mtile * 32;

    for (int idx = tid; idx < 32 * 181; idx += 256) sIn[idx] = in[(size_t)row0 * 181 + idx];

    const int nStart = half * 3620, nEnd = nStart + 3620;
    const int r = tid & 31, c8 = tid >> 5;
    float accO[12];
    #pragma unroll
    for (int j = 0; j < 12; ++j) accO[j] = 0.f;

    for (int n0 = nStart; n0 < nEnd; n0 += 64) {
        const int bn = min(64, nEnd - n0);   // 64 or 36 (both %4==0)
        __syncthreads();                     // prev phase2 done before sW1/sHid reuse
        for (int idx = tid; idx < bn * 181; idx += 256) {
            int n = idx / 181, k = idx - n * 181;
            sW1[n * 184 + k] = W1[(size_t)n0 * 181 + idx];
        }
        __syncthreads();
        // phase 1: hid[32][64] = relu(sIn @ sW1^T + b1)
        float acc1[8];
        #pragma unroll
        for (int cc = 0; cc < 8; ++cc) acc1[cc] = 0.f;
        for (int k = 0; k < 180; k += 4) {
            float a0 = sIn[r * 181 + k],     a1 = sIn[r * 181 + k + 1];
            float a2 = sIn[r * 181 + k + 2], a3 = sIn[r * 181 + k + 3];
            #pragma unroll
            for (int cc = 0; cc < 8; ++cc) {
                const float4 w = *(const float4*)&sW1[(c8 * 8 + cc) * 184 + k];
                acc1[cc] += a0 * w.x + a1 * w.y + a2 * w.z + a3 * w.w;
            }
        }
        {
            float a0 = sIn[r * 181 + 180];
            #pragma unroll
            for (int cc = 0; cc < 8; ++cc) acc1[cc] += a0 * sW1[(c8 * 8 + cc) * 184 + 180];
        }
        #pragma unroll
        for (int cc = 0; cc < 8; ++cc) {
            int c = c8 * 8 + cc;
            int nidx = n0 + ((c < bn) ? c : 0);
            float h = (c < bn) ? fmaxf(acc1[cc] + b1[nidx], 0.f) : 0.f;
            sHid[r * 65 + c] = h;
        }
        __syncthreads();
        // phase 2: accO[32][90] += hid @ W2chunk^T
        for (int k = 0; k < bn; k += 4) {
            float h0v = sHid[r * 65 + k],     h1 = sHid[r * 65 + k + 1];
            float h2  = sHid[r * 65 + k + 2], h3 = sHid[r * 65 + k + 3];
            #pragma unroll
            for (int j = 0; j < 12; ++j) {
                int m = c8 + (j << 3);
                if (m < 90) {
                    const float4 w = *(const float4*)&W2[(size_t)m * 7240 + n0 + k];
                    accO[j] += h0v * w.x + h1 * w.y + h2 * w.z + h3 * w.w;
                }
            }
        }
    }
    #pragma unroll
    for (int j = 0; j < 12; ++j) {
        int m = c8 + (j << 3);
        if (m < 90) partial[(size_t)half * B * 90 + (size_t)(row0 + r) * 90 + m] = accO[j];
    }
}

__global__ void fc2_combine(const float* __restrict__ partial, const float* __restrict__ b2,
                            float* __restrict__ kg, float* __restrict__ in3, int B) {
    int idx = blockIdx.x * 256 + threadIdx.x;
    if (idx < B * 90) {
        int b = idx / 90, m = idx - b * 90;
        float v = partial[idx] + partial[(size_t)B * 90 + idx] + b2[m];
        kg[idx] = v;                          // KG output (first in d_out)
        in3[(size_t)b * 171 + 81 + m] = v;    // FC3 input cols 81..170
    }
}

extern "C" void kernel_launch(void* const* d_in, const int* in_sizes, int n_in,
                              void* d_out, int out_size, void* d_ws, size_t ws_size,
                              hipStream_t stream) {
    const float* obs_diff  = (const float*)d_in[0];
    const float* obs_innov = (const float*)d_in[1];
    const float* fw_evol   = (const float*)d_in[2];
    const float* fw_upd    = (const float*)d_in[3];
    const float* Q_Wih  = (const float*)d_in[4];
    const float* Q_Whh  = (const float*)d_in[5];
    const float* Q_bih  = (const float*)d_in[6];
    const float* Q_bhh  = (const float*)d_in[7];
    const float* Sig_Wih = (const float*)d_in[8];
    const float* Sig_Whh = (const float*)d_in[9];   (void)Sig_Whh;
    const float* Sig_bih = (const float*)d_in[10];
    const float* Sig_bhh = (const float*)d_in[11];
    const float* S_Wih  = (const float*)d_in[12];
    const float* S_Whh  = (const float*)d_in[13];
    const float* S_bih  = (const float*)d_in[14];
    const float* S_bhh  = (const float*)d_in[15];
    const float* R_Wih  = (const float*)d_in[16];
    const float* R_Whh  = (const float*)d_in[17];
    const float* R_bih  = (const float*)d_in[18];
    const float* R_bhh  = (const float*)d_in[19];
    const float* fc1_W = (const float*)d_in[20];
    const float* fc1_b = (const float*)d_in[21];
    const float* fc2_W1 = (const float*)d_in[22];
    const float* fc2_b1 = (const float*)d_in[23];
    const float* fc2_W2 = (const float*)d_in[24];
    const float* fc2_b2 = (const float*)d_in[25];
    const float* fc3_W = (const float*)d_in[26];
    const float* fc3_b = (const float*)d_in[27];
    const float* fc4_W = (const float*)d_in[28];
    const float* fc4_b = (const float*)d_in[29];
    const float* fc5_W = (const float*)d_in[30];
    const float* fc5_b = (const float*)d_in[31];
    const float* fc6_W = (const float*)d_in[32];
    const float* fc6_b = (const float*)d_in[33];
    const float* fc7_W = (const float*)d_in[34];
    const float* fc7_b = (const float*)d_in[35];
    const float* fc8_W = (const float*)d_in[36];
    const float* fc8_b = (const float*)d_in[37];

    const int B = in_sizes[0] / MD;   // 8192
    float* ws = (float*)d_ws;
    float* gh = ws;                   // ghQ@0[300], ghR@320[243], ghS@576[243]
    size_t off = 1024;
    float* out5  = ws + off; off += (size_t)B * 50;
    float* inSig = ws + off; off += (size_t)B * 150;  // [hQ | FC6]
    float* out8  = ws + off; off += (size_t)B * 45;
    float* inS   = ws + off; off += (size_t)B * 207;  // [FC1 | FC7 | hR]
    float* inFC2 = ws + off; off += (size_t)B * 181;  // [hSigma | hS]
    float* in3   = ws + off; off += (size_t)B * 171;  // [hS | outFC2]
    float* in4   = ws + off; off += (size_t)B * 200;  // [hSigma | FC3]
    float* part  = ws + off; off += (size_t)B * 180;  // 2 x [B,90]

    float* out = (float*)d_out;
    float* o_kg  = out;
    float* o_hS  = out + (size_t)B * 90;
    float* o_hSn = out + (size_t)B * 171;
    float* o_hQ  = out + (size_t)B * 271;
    float* o_hR  = out + (size_t)B * 371;

    const int MB = B / 32;  // 256 blocks of 32 rows

    hipLaunchKernelGGL(gh_precompute, dim3(1), dim3(512), 0, stream,
                       Q_Whh, Q_bhh, R_Whh, R_bhh, S_Whh, S_bhh, gh);
    // FC5..FC8 with fused L2-normalization of the raw inputs
    hipLaunchKernelGGL(fc_kernel, dim3(MB), dim3(256), 0, stream,
                       fw_upd, SD, 0, SD, fc5_W, fc5_b, 50, 1, 1, out5, 50, 0);
    hipLaunchKernelGGL(fc_kernel, dim3(MB), dim3(256), 0, stream,
                       fw_evol, SD, 0, SD, fc6_W, fc6_b, 50, 1, 1, inSig, 150, 100);
    hipLaunchKernelGGL(fc_kernel, dim3(MB), dim3(256), 0, stream,
                       obs_diff, MD, 0, MD, fc7_W, fc7_b, 45, 1, 1, inS, 207, 81);
    hipLaunchKernelGGL(fc_kernel, dim3(MB), dim3(256), 0, stream,
                       obs_innov, MD, 0, MD, fc8_W, fc8_b, 45, 1, 1, out8, 45, 0);
    // GRU_Q -> hQ (to inSig cols 0..99 and d_out)
    hipLaunchKernelGGL(gru_kernel, dim3(MB), dim3(256), 0, stream,
                       out5, 50, Q_Wih, Q_bih, gh + 0, 100, 11,
                       inSig, 150, 0, o_hQ, 100, 0, (float*)nullptr, 0, 0);
    // GRU_Sigma (h0=0 -> gh = Sig_bhh) -> hSigma (inFC2 cols 0..99, in4 cols 0..99)
    hipLaunchKernelGGL(gru_kernel, dim3(MB), dim3(256), 0, stream,
                       inSig, 150, Sig_Wih, Sig_bih, Sig_bhh, 100, 0,
                       inFC2, 181, 0, in4, 200, 0, (float*)nullptr, 0, 0);
    // FC1(hSigma) -> inS cols 0..80
    hipLaunchKernelGGL(fc_kernel, dim3(MB), dim3(256), 0, stream,
                       inFC2, 181, 0, 100, fc1_W, fc1_b, 81, 1, 0, inS, 207, 0);
    // GRU_R -> hR (inS cols 126..206 and d_out)
    hipLaunchKernelGGL(gru_kernel, dim3(MB), dim3(256), 0, stream,
                       out8, 45, R_Wih, R_bih, gh + 320, 81, 10,
                       inS, 207, 126, o_hR, 81, 0, (float*)nullptr, 0, 0);
    // GRU_S -> hS (inFC2 cols 100..180, in3 cols 0..80, d_out)
    hipLaunchKernelGGL(gru_kernel, dim3(MB), dim3(256), 0, stream,
                       inS, 207, S_Wih, S_bih, gh + 576, 81, 10,
                       inFC2, 181, 100, in3, 171, 0, o_hS, 81, 0);
    // FC2 (fused 181->7240->90), N split across 2 block groups
    hipLaunchKernelGGL(fc2_fused, dim3(2 * MB), dim3(256), 0, stream,
                       inFC2, fc2_W1, fc2_b1, fc2_W2, part, B);
    hipLaunchKernelGGL(fc2_combine, dim3((B * 90 + 255) / 256), dim3(256), 0, stream,
                       part, fc2_b2, o_kg, in3, B);
    // FC3(concat(hS,outFC2)) -> in4 cols 100..199
    hipLaunchKernelGGL(fc_kernel, dim3(MB), dim3(256), 0, stream,
                       in3, 171, 0, 171, fc3_W, fc3_b, 100, 1, 0, in4, 200, 100);
    // FC4(concat(hSigma,FC3)) -> h_Sigma_new output
    hipLaunchKernelGGL(fc_kernel, dim3(MB), dim3(256), 0, stream,
                       in4, 200, 0, 200, fc4_W, fc4_b, 100, 1, 0, o_hSn, 100, 0);
}

// Round 2
// 478.876 us; speedup vs baseline: 4.8508x; 4.8508x over previous
//
#include <hip/hip_runtime.h>
#include <math.h>

#define SD 10
#define MD 9

typedef short bf8 __attribute__((ext_vector_type(8)));
typedef float f32x4 __attribute__((ext_vector_type(4)));

__device__ inline ushort f2b(float f) {
    union { float f; unsigned u; } v; v.f = f;
    unsigned r = v.u + 0x7FFF + ((v.u >> 16) & 1);
    return (ushort)(r >> 16);
}

// ---------------- constant gh precompute (h0 is batch-constant) ----------------
__global__ void gh_precompute(const float* __restrict__ Q_Whh, const float* __restrict__ Q_bhh,
                              const float* __restrict__ R_Whh, const float* __restrict__ R_bhh,
                              const float* __restrict__ S_Whh, const float* __restrict__ S_bhh,
                              float* __restrict__ gh) {
    int j = threadIdx.x;
    if (j < 300) {
        float s = Q_bhh[j];
        #pragma unroll
        for (int i = 0; i < 10; ++i) s += Q_Whh[j * 100 + 11 * i];
        gh[j] = s;
    }
    if (j < 243) {
        float s = R_bhh[j];
        #pragma unroll
        for (int i = 0; i < 9; ++i) s += R_Whh[j * 81 + 10 * i];
        gh[320 + j] = s;
        float s2 = S_bhh[j];
        #pragma unroll
        for (int i = 0; i < 9; ++i) s2 += S_Whh[j * 81 + 10 * i];
        gh[576 + j] = s2;
    }
}

// ---------------- weight converts for MFMA FC2 ----------------
// W1 [7240,181] f32 -> W1b [7296][192] bf16, zero-padded, 16B-chunk XOR-swizzled:
// position p within row holds logical chunk p^(r&7)  (involution)
__global__ void convert_w1(const float* __restrict__ W1, ushort* __restrict__ W1b) {
    int idx = blockIdx.x * 256 + threadIdx.x;
    if (idx >= 7296 * 24) return;
    int r = idx / 24, p = idx - r * 24;
    int cs = p ^ (r & 7);
    union { ushort u[8]; uint4 v; } o;
    #pragma unroll
    for (int j = 0; j < 8; ++j) {
        int k = cs * 8 + j;
        float val = (r < 7240 && k < 181) ? W1[(size_t)r * 181 + k] : 0.f;
        o.u[j] = f2b(val);
    }
    *(uint4*)(W1b + (size_t)r * 192 + p * 8) = o.v;
}

// W2 [90,7240] f32 -> W2b [96][7296] bf16, zero-padded, linear
__global__ void convert_w2(const float* __restrict__ W2, ushort* __restrict__ W2b) {
    int idx = blockIdx.x * 256 + threadIdx.x;
    if (idx >= 96 * 912) return;
    int r = idx / 912, p = idx - r * 912;
    union { ushort u[8]; uint4 v; } o;
    #pragma unroll
    for (int j = 0; j < 8; ++j) {
        int k = p * 8 + j;
        float val = (r < 90 && k < 7240) ? W2[(size_t)r * 7240 + k] : 0.f;
        o.u[j] = f2b(val);
    }
    *(uint4*)(W2b + (size_t)r * 7296 + p * 8) = o.v;
}

// ---------------- generic small FC ----------------
__global__ __launch_bounds__(256) void fc_kernel(
    const float* __restrict__ in, int in_ld, int in_off, int K,
    const float* __restrict__ W, const float* __restrict__ bias, int N,
    int do_relu, int do_norm,
    float* __restrict__ dst, int dld, int doff) {
    __shared__ float sIn[32 * 208];
    __shared__ float sScale[32];
    const int tid = threadIdx.x;
    const int row0 = blockIdx.x * 32;
    const int KP = (K & 1) ? K : K + 1;

    for (int idx = tid; idx < 32 * K; idx += 256) {
        int r = idx / K, k = idx - r * K;
        sIn[r * KP + k] = in[(size_t)(row0 + r) * in_ld + in_off + k];
    }
    __syncthreads();
    if (do_norm) {
        if (tid < 32) {
            float s = 0.f;
            for (int k = 0; k < K; ++k) { float v = sIn[tid * KP + k]; s += v * v; }
            sScale[tid] = 1.0f / fmaxf(sqrtf(s), 1e-12f);
        }
        __syncthreads();
    }
    for (int idx = tid; idx < 32 * N; idx += 256) {
        int r = idx & 31, n = idx >> 5;
        float acc = 0.f;
        int k = 0;
        for (; k + 4 <= K; k += 4) {
            acc += sIn[r * KP + k]     * W[n * K + k];
            acc += sIn[r * KP + k + 1] * W[n * K + k + 1];
            acc += sIn[r * KP + k + 2] * W[n * K + k + 2];
            acc += sIn[r * KP + k + 3] * W[n * K + k + 3];
        }
        for (; k < K; ++k) acc += sIn[r * KP + k] * W[n * K + k];
        if (do_norm) acc *= sScale[r];
        acc += bias[n];
        if (do_relu) acc = fmaxf(acc, 0.f);
        dst[(size_t)(row0 + r) * dld + doff + n] = acc;
    }
}

// ---------------- GRU with constant hidden ----------------
__global__ __launch_bounds__(256) void gru_kernel(
    const float* __restrict__ in, int K,
    const float* __restrict__ Wih, const float* __restrict__ bih,
    const float* __restrict__ gh, int H, int h0p,
    float* __restrict__ d0, int ld0, int o0,
    float* __restrict__ d1, int ld1, int o1,
    ushort* __restrict__ db, int ldb, int ob) {
    __shared__ float sIn[32 * 208];
    __shared__ float sGi[32 * 301];
    const int tid = threadIdx.x;
    const int row0 = blockIdx.x * 32;
    const int KP = (K & 1) ? K : K + 1;
    const int N = 3 * H;
    const int GP = (N & 1) ? N : N + 1;

    for (int idx = tid; idx < 32 * K; idx += 256) {
        int r = idx / K, k = idx - r * K;
        sIn[r * KP + k] = in[(size_t)row0 * K + idx];
    }
    __syncthreads();
    for (int idx = tid; idx < 32 * N; idx += 256) {
        int r = idx & 31, n = idx >> 5;
        float acc = bih[n];
        int k = 0;
        for (; k + 4 <= K; k += 4) {
            acc += sIn[r * KP + k]     * Wih[n * K + k];
            acc += sIn[r * KP + k + 1] * Wih[n * K + k + 1];
            acc += sIn[r * KP + k + 2] * Wih[n * K + k + 2];
            acc += sIn[r * KP + k + 3] * Wih[n * K + k + 3];
        }
        for (; k < K; ++k) acc += sIn[r * KP + k] * Wih[n * K + k];
        sGi[r * GP + n] = acc;
    }
    __syncthreads();
    for (int idx = tid; idx < 32 * H; idx += 256) {
        int r = idx & 31, h = idx >> 5;
        float ir = sGi[r * GP + h];
        float iz = sGi[r * GP + H + h];
        float inn = sGi[r * GP + 2 * H + h];
        float rr = 1.f / (1.f + expf(-(ir + gh[h])));
        float zz = 1.f / (1.f + expf(-(iz + gh[H + h])));
        float nn = tanhf(inn + rr * gh[2 * H + h]);
        float h0 = (h0p > 0 && (h % h0p) == 0) ? 1.f : 0.f;
        float v = (1.f - zz) * nn + zz * h0;
        size_t rw = (size_t)(row0 + r);
        d0[rw * ld0 + o0 + h] = v;
        if (d1) d1[rw * ld1 + o1 + h] = v;
        if (db) db[rw * ldb + ob + h] = f2b(v);
    }
}

// ---------------- FC2 via bf16 MFMA, fully fused ----------------
// Xb [B][192] bf16 (cols 0..180 valid, pad garbage harmless: W1b pad rows/cols are 0)
// W1b [7296][192] bf16 swizzled; W2b [96][7296] bf16; partial [4][B][96] f32
__global__ __launch_bounds__(256, 2) void fc2_mfma(
    const ushort* __restrict__ Xb, const ushort* __restrict__ W1b,
    const float* __restrict__ b1, const ushort* __restrict__ W2b,
    float* __restrict__ partial, int B) {
    __shared__ ushort sW1[64 * 192];        // 24576 B
    __shared__ ushort sHid[4][64 * 56];     // 28672 B, per-wave [64][56] strips
    const int tid = threadIdx.x;
    const int w = tid >> 6, l = tid & 63;
    const int lr = l & 15, lk = l >> 4;
    const int bid = blockIdx.x;
    const int mt = bid >> 2, split = bid & 3;   // same-split blocks share an XCD slice
    const int m0 = mt * 64;
    const int u0 = (57 * split) / 4, u1 = (57 * (split + 1)) / 4;

    // persistent A-frags: X rows m0..m0+63, K=192 (24 x bf16x8 = 96 VGPR)
    bf8 A[4][6];
    {
        const ushort* xp = Xb + (size_t)(m0 + lr) * 192 + lk * 8;
        #pragma unroll
        for (int mi = 0; mi < 4; ++mi)
            #pragma unroll
            for (int ks = 0; ks < 6; ++ks)
                A[mi][ks] = *(const bf8*)(xp + (size_t)mi * 16 * 192 + ks * 32);
    }

    f32x4 acc2[4][6];
    #pragma unroll
    for (int mi = 0; mi < 4; ++mi)
        #pragma unroll
        for (int nj = 0; nj < 6; ++nj) acc2[mi][nj] = (f32x4){0.f, 0.f, 0.f, 0.f};

    ushort* myHid = &sHid[w][0];
    const int nloc = w * 16 + lr;   // wave's W1 row within a 64-chunk

    for (int u = u0; u < u1; ++u) {
        const int n0 = u * 128;
        #pragma unroll
        for (int h = 0; h < 2; ++h) {
            __syncthreads();   // protect sW1 from previous readers
            // stage 64 rows x 384B = 24KB via global_load_lds (linear; data pre-swizzled)
            #pragma unroll
            for (int p = 0; p < 6; ++p) {
                const ushort* g = W1b + (size_t)(n0 + h * 64) * 192 + (p * 4 + w) * 512 + l * 8;
                __builtin_amdgcn_global_load_lds(
                    (const __attribute__((address_space(1))) unsigned int*)g,
                    (__attribute__((address_space(3))) unsigned int*)(sW1 + (p * 4 + w) * 512),
                    16, 0, 0);
            }
            asm volatile("s_waitcnt vmcnt(0)" ::: "memory");
            __syncthreads();

            // GEMM1: hid[64][16-strip] = X @ W1chunk^T
            f32x4 acc1[4];
            #pragma unroll
            for (int mi = 0; mi < 4; ++mi) acc1[mi] = (f32x4){0.f, 0.f, 0.f, 0.f};
            #pragma unroll
            for (int ks = 0; ks < 6; ++ks) {
                int cs = ks * 4 + lk;
                int p = cs ^ (nloc & 7);   // undo the pre-swizzle -> conflict-free
                bf8 Bf = *(const bf8*)(sW1 + nloc * 192 + p * 8);
                #pragma unroll
                for (int mi = 0; mi < 4; ++mi)
                    acc1[mi] = __builtin_amdgcn_mfma_f32_16x16x32_bf16(A[mi][ks], Bf, acc1[mi], 0, 0, 0);
            }
            // bias + relu + bf16 -> per-wave hid strip (cols h*16..h*16+15)
            int gn = n0 + h * 64 + nloc;
            float bias = (gn < 7240) ? b1[gn] : 0.f;
            #pragma unroll
            for (int mi = 0; mi < 4; ++mi)
                #pragma unroll
                for (int q = 0; q < 4; ++q) {
                    float v = fmaxf(acc1[mi][q] + bias, 0.f);
                    myHid[(mi * 16 + lk * 4 + q) * 56 + h * 16 + lr] = f2b(v);
                }
        }
        // GEMM2: out[64][96] += hid_strip[64][32] @ W2(strip cols)^T  (wave-local)
        bf8 aF[4];
        #pragma unroll
        for (int mi = 0; mi < 4; ++mi)
            aF[mi] = *(const bf8*)(myHid + (mi * 16 + lr) * 56 + lk * 8);
        const size_t kbase = (size_t)n0 + (lk >> 1) * 64 + w * 16 + (lk & 1) * 8;
        #pragma unroll
        for (int nj = 0; nj < 6; ++nj) {
            bf8 Bf2 = *(const bf8*)(W2b + (size_t)(nj * 16 + lr) * 7296 + kbase);
            #pragma unroll
            for (int mi = 0; mi < 4; ++mi)
                acc2[mi][nj] = __builtin_amdgcn_mfma_f32_16x16x32_bf16(aF[mi], Bf2, acc2[mi][nj], 0, 0, 0);
        }
    }

    // cross-wave reduction: waves 1,3 write; waves 0,2 add; then sum halves to global
    float* red1 = (float*)sW1;          // 64*96*4 = 24576 B exactly
    float* red2 = (float*)&sHid[0][0];  // 28672 B >= 24576
    __syncthreads();
    if (w == 1 || w == 3) {
        float* r_ = (w == 1) ? red1 : red2;
        #pragma unroll
        for (int mi = 0; mi < 4; ++mi)
            #pragma unroll
            for (int nj = 0; nj < 6; ++nj)
                #pragma unroll
                for (int q = 0; q < 4; ++q)
                    r_[(mi * 16 + lk * 4 + q) * 96 + nj * 16 + lr] = acc2[mi][nj][q];
    }
    __syncthreads();
    if (w == 0 || w == 2) {
        float* r_ = (w == 0) ? red1 : red2;
        #pragma unroll
        for (int mi = 0; mi < 4; ++mi)
            #pragma unroll
            for (int nj = 0; nj < 6; ++nj)
                #pragma unroll
                for (int q = 0; q < 4; ++q)
                    r_[(mi * 16 + lk * 4 + q) * 96 + nj * 16 + lr] += acc2[mi][nj][q];
    }
    __syncthreads();
    float* dst = partial + ((size_t)split * B + m0) * 96;
    for (int i = tid; i < 64 * 96; i += 256) dst[i] = red1[i] + red2[i];
}

__global__ void fc2_combine(const float* __restrict__ partial, const float* __restrict__ b2,
                            float* __restrict__ kg, float* __restrict__ in3, int B) {
    int idx = blockIdx.x * 256 + threadIdx.x;
    if (idx < B * 90) {
        int b = idx / 90, m = idx - b * 90;
        size_t p = (size_t)b * 96 + m, s = (size_t)B * 96;
        float v = partial[p] + partial[p + s] + partial[p + 2 * s] + partial[p + 3 * s] + b2[m];
        kg[idx] = v;
        in3[(size_t)b * 171 + 81 + m] = v;
    }
}

extern "C" void kernel_launch(void* const* d_in, const int* in_sizes, int n_in,
                              void* d_out, int out_size, void* d_ws, size_t ws_size,
                              hipStream_t stream) {
    const float* obs_diff  = (const float*)d_in[0];
    const float* obs_innov = (const float*)d_in[1];
    const float* fw_evol   = (const float*)d_in[2];
    const float* fw_upd    = (const float*)d_in[3];
    const float* Q_Wih  = (const float*)d_in[4];
    const float* Q_Whh  = (const float*)d_in[5];
    const float* Q_bih  = (const float*)d_in[6];
    const float* Q_bhh  = (const float*)d_in[7];
    const float* Sig_Wih = (const float*)d_in[8];
    const float* Sig_bih = (const float*)d_in[10];
    const float* Sig_bhh = (const float*)d_in[11];
    const float* S_Wih  = (const float*)d_in[12];
    const float* S_Whh  = (const float*)d_in[13];
    const float* S_bih  = (const float*)d_in[14];
    const float* S_bhh  = (const float*)d_in[15];
    const float* R_Wih  = (const float*)d_in[16];
    const float* R_Whh  = (const float*)d_in[17];
    const float* R_bih  = (const float*)d_in[18];
    const float* R_bhh  = (const float*)d_in[19];
    const float* fc1_W = (const float*)d_in[20];
    const float* fc1_b = (const float*)d_in[21];
    const float* fc2_W1 = (const float*)d_in[22];
    const float* fc2_b1 = (const float*)d_in[23];
    const float* fc2_W2 = (const float*)d_in[24];
    const float* fc2_b2 = (const float*)d_in[25];
    const float* fc3_W = (const float*)d_in[26];
    const float* fc3_b = (const float*)d_in[27];
    const float* fc4_W = (const float*)d_in[28];
    const float* fc4_b = (const float*)d_in[29];
    const float* fc5_W = (const float*)d_in[30];
    const float* fc5_b = (const float*)d_in[31];
    const float* fc6_W = (const float*)d_in[32];
    const float* fc6_b = (const float*)d_in[33];
    const float* fc7_W = (const float*)d_in[34];
    const float* fc7_b = (const float*)d_in[35];
    const float* fc8_W = (const float*)d_in[36];
    const float* fc8_b = (const float*)d_in[37];

    const int B = in_sizes[0] / MD;   // 8192
    float* ws = (float*)d_ws;
    float* gh = ws;
    size_t off = 1024;
    float* out5  = ws + off; off += (size_t)B * 50;
    float* inSig = ws + off; off += (size_t)B * 150;  // [hQ | FC6]
    float* out8  = ws + off; off += (size_t)B * 45;
    float* inS   = ws + off; off += (size_t)B * 207;  // [FC1 | FC7 | hR]
    float* in3   = ws + off; off += (size_t)B * 171;  // [hS | outFC2]
    float* in4   = ws + off; off += (size_t)B * 200;  // [hSigma | FC3]
    ushort* Xb   = (ushort*)(ws + off); off += (size_t)B * 96;    // [B][192] bf16
    ushort* W1b  = (ushort*)(ws + off); off += 700416;            // [7296][192] bf16
    ushort* W2b  = (ushort*)(ws + off); off += 350208;            // [96][7296] bf16
    float* part  = ws + off; off += (size_t)4 * B * 96;

    float* out = (float*)d_out;
    float* o_kg  = out;
    float* o_hS  = out + (size_t)B * 90;
    float* o_hSn = out + (size_t)B * 171;
    float* o_hQ  = out + (size_t)B * 271;
    float* o_hR  = out + (size_t)B * 371;

    const int MB = B / 32;

    hipLaunchKernelGGL(gh_precompute, dim3(1), dim3(512), 0, stream,
                       Q_Whh, Q_bhh, R_Whh, R_bhh, S_Whh, S_bhh, gh);
    hipLaunchKernelGGL(convert_w1, dim3((7296 * 24 + 255) / 256), dim3(256), 0, stream, fc2_W1, W1b);
    hipLaunchKernelGGL(convert_w2, dim3((96 * 912 + 255) / 256), dim3(256), 0, stream, fc2_W2, W2b);
    // FC5..FC8 with fused L2-normalization
    hipLaunchKernelGGL(fc_kernel, dim3(MB), dim3(256), 0, stream,
                       fw_upd, SD, 0, SD, fc5_W, fc5_b, 50, 1, 1, out5, 50, 0);
    hipLaunchKernelGGL(fc_kernel, dim3(MB), dim3(256), 0, stream,
                       fw_evol, SD, 0, SD, fc6_W, fc6_b, 50, 1, 1, inSig, 150, 100);
    hipLaunchKernelGGL(fc_kernel, dim3(MB), dim3(256), 0, stream,
                       obs_diff, MD, 0, MD, fc7_W, fc7_b, 45, 1, 1, inS, 207, 81);
    hipLaunchKernelGGL(fc_kernel, dim3(MB), dim3(256), 0, stream,
                       obs_innov, MD, 0, MD, fc8_W, fc8_b, 45, 1, 1, out8, 45, 0);
    // GRU_Q -> hQ
    hipLaunchKernelGGL(gru_kernel, dim3(MB), dim3(256), 0, stream,
                       out5, 50, Q_Wih, Q_bih, gh + 0, 100, 11,
                       inSig, 150, 0, o_hQ, 100, 0, (ushort*)nullptr, 0, 0);
    // GRU_Sigma -> hSigma (in4 cols 0..99 f32, Xb cols 0..99 bf16)
    hipLaunchKernelGGL(gru_kernel, dim3(MB), dim3(256), 0, stream,
                       inSig, 150, Sig_Wih, Sig_bih, Sig_bhh, 100, 0,
                       in4, 200, 0, (float*)nullptr, 0, 0, Xb, 192, 0);
    // FC1(hSigma from in4) -> inS cols 0..80
    hipLaunchKernelGGL(fc_kernel, dim3(MB), dim3(256), 0, stream,
                       in4, 200, 0, 100, fc1_W, fc1_b, 81, 1, 0, inS, 207, 0);
    // GRU_R -> hR
    hipLaunchKernelGGL(gru_kernel, dim3(MB), dim3(256), 0, stream,
                       out8, 45, R_Wih, R_bih, gh + 320, 81, 10,
                       inS, 207, 126, o_hR, 81, 0, (ushort*)nullptr, 0, 0);
    // GRU_S -> hS (in3 cols 0..80, d_out, Xb cols 100..180 bf16)
    hipLaunchKernelGGL(gru_kernel, dim3(MB), dim3(256), 0, stream,
                       inS, 207, S_Wih, S_bih, gh + 576, 81, 10,
                       in3, 171, 0, o_hS, 81, 0, Xb, 192, 100);
    // FC2 via MFMA (181->7240->90 fused), 4-way N-split
    hipLaunchKernelGGL(fc2_mfma, dim3((B / 64) * 4), dim3(256), 0, stream,
                       Xb, W1b, fc2_b1, W2b, part, B);
    hipLaunchKernelGGL(fc2_combine, dim3((B * 90 + 255) / 256), dim3(256), 0, stream,
                       part, fc2_b2, o_kg, in3, B);
    // FC3 -> in4 cols 100..199
    hipLaunchKernelGGL(fc_kernel, dim3(MB), dim3(256), 0, stream,
                       in3, 171, 0, 171, fc3_W, fc3_b, 100, 1, 0, in4, 200, 100);
    // FC4 -> h_Sigma_new
    hipLaunchKernelGGL(fc_kernel, dim3(MB), dim3(256), 0, stream,
                       in4, 200, 0, 200, fc4_W, fc4_b, 100, 1, 0, o_hSn, 100, 0);
}

// Round 3
// 233.206 us; speedup vs baseline: 9.9609x; 2.0534x over previous
//
#include <hip/hip_runtime.h>
#include <math.h>

#define SD 10
#define MD 9

typedef short bf8 __attribute__((ext_vector_type(8)));
typedef float f32x4 __attribute__((ext_vector_type(4)));

__device__ inline ushort f2b(float f) {
    union { float f; unsigned u; } v; v.f = f;
    unsigned r = v.u + 0x7FFF + ((v.u >> 16) & 1);
    return (ushort)(r >> 16);
}

// ---------------- constant gh precompute (h0 is batch-constant) ----------------
__global__ void gh_precompute(const float* __restrict__ Q_Whh, const float* __restrict__ Q_bhh,
                              const float* __restrict__ R_Whh, const float* __restrict__ R_bhh,
                              const float* __restrict__ S_Whh, const float* __restrict__ S_bhh,
                              float* __restrict__ gh) {
    int j = threadIdx.x;
    if (j < 300) {
        float s = Q_bhh[j];
        #pragma unroll
        for (int i = 0; i < 10; ++i) s += Q_Whh[j * 100 + 11 * i];
        gh[j] = s;
    }
    if (j < 243) {
        float s = R_bhh[j];
        #pragma unroll
        for (int i = 0; i < 9; ++i) s += R_Whh[j * 81 + 10 * i];
        gh[320 + j] = s;
        float s2 = S_bhh[j];
        #pragma unroll
        for (int i = 0; i < 9; ++i) s2 += S_Whh[j * 81 + 10 * i];
        gh[576 + j] = s2;
    }
}

// ---------------- pad-copy small weights to K%4==0 strides (zero pad) ----------------
// segments (dst offset in floats, N, K, KP):
// 0:fc5[50,10,12]@0  1:fc6[50,10,12]@600  2:fc7[45,9,12]@1200  3:fc8[45,9,12]@1740
// 4:Q_Wih[300,50,52]@2280  5:Sig_Wih[300,150,152]@17880  6:R_Wih[243,45,48]@63480
// 7:S_Wih[243,207,208]@75144  8:fc3_W[100,171,172]@125688   total 142888
#define WPAD_TOTAL 142888
__global__ void prep_weights(const float* __restrict__ w5, const float* __restrict__ w6,
                             const float* __restrict__ w7, const float* __restrict__ w8,
                             const float* __restrict__ wq, const float* __restrict__ wsig,
                             const float* __restrict__ wr, const float* __restrict__ wss,
                             const float* __restrict__ w3, float* __restrict__ dst) {
    int idx = blockIdx.x * 256 + threadIdx.x;
    if (idx >= WPAD_TOTAL) return;
    const int offs[10] = {0, 600, 1200, 1740, 2280, 17880, 63480, 75144, 125688, WPAD_TOTAL};
    const int Ks[9]  = {10, 10, 9, 9, 50, 150, 45, 207, 171};
    const int KPs[9] = {12, 12, 12, 12, 52, 152, 48, 208, 172};
    const float* srcs[9] = {w5, w6, w7, w8, wq, wsig, wr, wss, w3};
    int s = 0;
    #pragma unroll
    for (int i = 1; i < 9; ++i) if (idx >= offs[i]) s = i;
    int loc = idx - offs[s];
    int KP = KPs[s], K = Ks[s];
    int r = loc / KP, k = loc - r * KP;
    dst[idx] = (k < K) ? srcs[s][r * K + k] : 0.f;
}

// ---------------- weight converts for MFMA FC2 ----------------
__global__ void convert_w1(const float* __restrict__ W1, ushort* __restrict__ W1b) {
    int idx = blockIdx.x * 256 + threadIdx.x;
    if (idx >= 7296 * 24) return;
    int r = idx / 24, p = idx - r * 24;
    int cs = p ^ (r & 7);
    union { ushort u[8]; uint4 v; } o;
    #pragma unroll
    for (int j = 0; j < 8; ++j) {
        int k = cs * 8 + j;
        float val = (r < 7240 && k < 181) ? W1[(size_t)r * 181 + k] : 0.f;
        o.u[j] = f2b(val);
    }
    *(uint4*)(W1b + (size_t)r * 192 + p * 8) = o.v;
}

__global__ void convert_w2(const float* __restrict__ W2, ushort* __restrict__ W2b) {
    int idx = blockIdx.x * 256 + threadIdx.x;
    if (idx >= 96 * 912) return;
    int r = idx / 912, p = idx - r * 912;
    union { ushort u[8]; uint4 v; } o;
    #pragma unroll
    for (int j = 0; j < 8; ++j) {
        int k = p * 8 + j;
        float val = (r < 90 && k < 7240) ? W2[(size_t)r * 7240 + k] : 0.f;
        o.u[j] = f2b(val);
    }
    *(uint4*)(W2b + (size_t)r * 7296 + p * 8) = o.v;
}

// ---------------- ILP GEMM primitive: 2-row x 4-col micro-tiles ----------------
// sX: LDS [16][ldx] f32 (K-pad cols zeroed). W: [N][KP] (rows KP-strided, 16B-aligned).
// Writes act(acc+bias) to optional LDS dst and/or global dst.
__device__ __forceinline__ void gemm_tile(
    const float* sX, int ldx, int KP,
    const float* __restrict__ W, const float* __restrict__ bias, int N, int relu,
    float* sDst, int ldd, int doff,
    float* gDst, int gld, int goff, int row0, int tid) {
    const int NG = (N + 3) >> 2;
    for (int t = tid; t < 8 * NG; t += 256) {
        const int rp = t & 7, g = t >> 3;
        const int n0 = g * 4;
        int nn[4];
        #pragma unroll
        for (int j = 0; j < 4; ++j) nn[j] = min(n0 + j, N - 1);
        const float* x0 = sX + rp * ldx;
        const float* x1 = sX + (rp + 8) * ldx;
        const float* wp[4];
        #pragma unroll
        for (int j = 0; j < 4; ++j) wp[j] = W + (size_t)nn[j] * KP;
        float accA[4] = {0.f, 0.f, 0.f, 0.f};
        float accB[4] = {0.f, 0.f, 0.f, 0.f};
        #pragma unroll 2
        for (int k = 0; k < KP; k += 4) {
            float4 xa = *(const float4*)(x0 + k);
            float4 xb = *(const float4*)(x1 + k);
            #pragma unroll
            for (int j = 0; j < 4; ++j) {
                float4 w = *(const float4*)(wp[j] + k);
                accA[j] += xa.x * w.x + xa.y * w.y + xa.z * w.z + xa.w * w.w;
                accB[j] += xb.x * w.x + xb.y * w.y + xb.z * w.z + xb.w * w.w;
            }
        }
        #pragma unroll
        for (int j = 0; j < 4; ++j) {
            int n = n0 + j;
            if (n < N) {
                float b = bias[n];
                float vA = accA[j] + b, vB = accB[j] + b;
                if (relu) { vA = fmaxf(vA, 0.f); vB = fmaxf(vB, 0.f); }
                if (sDst) { sDst[rp * ldd + doff + n] = vA; sDst[(rp + 8) * ldd + doff + n] = vB; }
                if (gDst) {
                    gDst[(size_t)(row0 + rp) * gld + goff + n] = vA;
                    gDst[(size_t)(row0 + rp + 8) * gld + goff + n] = vB;
                }
            }
        }
    }
}

// ---------------- fused small-layer chain: FC5-8, GRU_Q/Sigma/R/S, FC1 ----------------
// 16 rows/block, 512 blocks. LDS layout (floats, zeroed at start):
#define L_FWU   0      // [16][12]
#define L_FWE   192
#define L_OBS   384
#define L_OBSI  576
#define L_SCALE 768    // [64]
#define L_OUT5  832    // [16][52]
#define L_OUT8  1664   // [16][48]
#define L_INSIG 2432   // [16][152]
#define L_INS   4864   // [16][208]
#define L_GI    8192   // [16][305]
#define L_HSIG  13072  // [16][104]
#define L_TOTAL 14736
__global__ __launch_bounds__(256) void chain_fused(
    const float* __restrict__ obs_diff, const float* __restrict__ obs_innov,
    const float* __restrict__ fw_evol, const float* __restrict__ fw_upd,
    const float* __restrict__ wpad, const float* __restrict__ gh,
    const float* __restrict__ Q_bih, const float* __restrict__ Sig_bih,
    const float* __restrict__ Sig_bhh,
    const float* __restrict__ R_bih, const float* __restrict__ S_bih,
    const float* __restrict__ fc1_W, const float* __restrict__ fc1_b,
    const float* __restrict__ fc5_b, const float* __restrict__ fc6_b,
    const float* __restrict__ fc7_b, const float* __restrict__ fc8_b,
    float* __restrict__ o_hQ, float* __restrict__ o_hR, float* __restrict__ o_hS,
    float* __restrict__ hSig_g, ushort* __restrict__ Xb) {
    __shared__ __align__(16) float sm[L_TOTAL];
    const int tid = threadIdx.x;
    const int row0 = blockIdx.x * 16;

    for (int i = tid; i < L_TOTAL; i += 256) sm[i] = 0.f;
    __syncthreads();

    // load raw inputs
    for (int i = tid; i < 16 * 10; i += 256) {
        int r = i / 10, k = i - r * 10;
        sm[L_FWU + r * 12 + k] = fw_upd[(size_t)(row0 + r) * 10 + k];
        sm[L_FWE + r * 12 + k] = fw_evol[(size_t)(row0 + r) * 10 + k];
    }
    for (int i = tid; i < 16 * 9; i += 256) {
        int r = i / 9, k = i - r * 9;
        sm[L_OBS + r * 12 + k]  = obs_diff[(size_t)(row0 + r) * 9 + k];
        sm[L_OBSI + r * 12 + k] = obs_innov[(size_t)(row0 + r) * 9 + k];
    }
    __syncthreads();
    // per-row L2 normalization in place
    if (tid < 64) {
        int v = tid >> 4, r = tid & 15;
        int base = (v == 0 ? L_FWU : v == 1 ? L_FWE : v == 2 ? L_OBS : L_OBSI) + r * 12;
        int len = (v < 2) ? 10 : 9;
        float s = 0.f;
        for (int k = 0; k < len; ++k) { float x = sm[base + k]; s += x * x; }
        float sc = 1.f / fmaxf(sqrtf(s), 1e-12f);
        for (int k = 0; k < len; ++k) sm[base + k] *= sc;
    }
    __syncthreads();
    // FC5 -> out5, FC6 -> inSig[100..149], FC7 -> inS[81..125], FC8 -> out8 (all relu)
    gemm_tile(sm + L_FWU, 12, 12, wpad + 0, fc5_b, 50, 1, sm + L_OUT5, 52, 0, nullptr, 0, 0, 0, tid);
    gemm_tile(sm + L_FWE, 12, 12, wpad + 600, fc6_b, 50, 1, sm + L_INSIG, 152, 100, nullptr, 0, 0, 0, tid);
    gemm_tile(sm + L_OBS, 12, 12, wpad + 1200, fc7_b, 45, 1, sm + L_INS, 208, 81, nullptr, 0, 0, 0, tid);
    gemm_tile(sm + L_OBSI, 12, 12, wpad + 1740, fc8_b, 45, 1, sm + L_OUT8, 48, 0, nullptr, 0, 0, 0, tid);
    __syncthreads();
    // GRU_Q: gi = out5 @ Q_Wih^T + Q_bih
    gemm_tile(sm + L_OUT5, 52, 52, wpad + 2280, Q_bih, 300, 0, sm + L_GI, 305, 0, nullptr, 0, 0, 0, tid);
    __syncthreads();
    // Q gates -> inSig[0..99] + o_hQ
    for (int i = tid; i < 16 * 100; i += 256) {
        int r = i / 100, h = i - r * 100;
        float ir = sm[L_GI + r * 305 + h], iz = sm[L_GI + r * 305 + 100 + h], in = sm[L_GI + r * 305 + 200 + h];
        float rr = 1.f / (1.f + __expf(-(ir + gh[h])));
        float zz = 1.f / (1.f + __expf(-(iz + gh[100 + h])));
        float t = in + rr * gh[200 + h];
        float nn = 1.f - 2.f / (1.f + __expf(2.f * t));
        float h0 = ((h % 11) == 0) ? 1.f : 0.f;
        float v = (1.f - zz) * nn + zz * h0;
        sm[L_INSIG + r * 152 + h] = v;
        o_hQ[(size_t)(row0 + r) * 100 + h] = v;
    }
    __syncthreads();
    // GRU_Sigma: gi = inSig @ Sig_Wih^T + Sig_bih
    gemm_tile(sm + L_INSIG, 152, 152, wpad + 17880, Sig_bih, 300, 0, sm + L_GI, 305, 0, nullptr, 0, 0, 0, tid);
    __syncthreads();
    // Sigma gates (h0=0, gh=Sig_bhh) -> hSigma LDS + hSig_g + Xb[0..99]
    for (int i = tid; i < 16 * 100; i += 256) {
        int r = i / 100, h = i - r * 100;
        float ir = sm[L_GI + r * 305 + h], iz = sm[L_GI + r * 305 + 100 + h], in = sm[L_GI + r * 305 + 200 + h];
        float rr = 1.f / (1.f + __expf(-(ir + Sig_bhh[h])));
        float zz = 1.f / (1.f + __expf(-(iz + Sig_bhh[100 + h])));
        float t = in + rr * Sig_bhh[200 + h];
        float nn = 1.f - 2.f / (1.f + __expf(2.f * t));
        float v = (1.f - zz) * nn;
        sm[L_HSIG + r * 104 + h] = v;
        hSig_g[(size_t)(row0 + r) * 100 + h] = v;
        Xb[(size_t)(row0 + r) * 192 + h] = f2b(v);
    }
    __syncthreads();
    // FC1(hSigma) -> inS[0..80] ; GRU_R: gi = out8 @ R_Wih^T + R_bih
    gemm_tile(sm + L_HSIG, 104, 100, fc1_W, fc1_b, 81, 1, sm + L_INS, 208, 0, nullptr, 0, 0, 0, tid);
    gemm_tile(sm + L_OUT8, 48, 48, wpad + 63480, R_bih, 243, 0, sm + L_GI, 305, 0, nullptr, 0, 0, 0, tid);
    __syncthreads();
    // R gates -> inS[126..206] + o_hR
    for (int i = tid; i < 16 * 81; i += 256) {
        int r = i / 81, h = i - r * 81;
        float ir = sm[L_GI + r * 305 + h], iz = sm[L_GI + r * 305 + 81 + h], in = sm[L_GI + r * 305 + 162 + h];
        float rr = 1.f / (1.f + __expf(-(ir + gh[320 + h])));
        float zz = 1.f / (1.f + __expf(-(iz + gh[320 + 81 + h])));
        float t = in + rr * gh[320 + 162 + h];
        float nn = 1.f - 2.f / (1.f + __expf(2.f * t));
        float h0 = ((h % 10) == 0) ? 1.f : 0.f;
        float v = (1.f - zz) * nn + zz * h0;
        sm[L_INS + r * 208 + 126 + h] = v;
        o_hR[(size_t)(row0 + r) * 81 + h] = v;
    }
    __syncthreads();
    // GRU_S: gi = inS @ S_Wih^T + S_bih
    gemm_tile(sm + L_INS, 208, 208, wpad + 75144, S_bih, 243, 0, sm + L_GI, 305, 0, nullptr, 0, 0, 0, tid);
    __syncthreads();
    // S gates -> o_hS + Xb[100..180]
    for (int i = tid; i < 16 * 81; i += 256) {
        int r = i / 81, h = i - r * 81;
        float ir = sm[L_GI + r * 305 + h], iz = sm[L_GI + r * 305 + 81 + h], in = sm[L_GI + r * 305 + 162 + h];
        float rr = 1.f / (1.f + __expf(-(ir + gh[576 + h])));
        float zz = 1.f / (1.f + __expf(-(iz + gh[576 + 81 + h])));
        float t = in + rr * gh[576 + 162 + h];
        float nn = 1.f - 2.f / (1.f + __expf(2.f * t));
        float h0 = ((h % 10) == 0) ? 1.f : 0.f;
        float v = (1.f - zz) * nn + zz * h0;
        o_hS[(size_t)(row0 + r) * 81 + h] = v;
        Xb[(size_t)(row0 + r) * 192 + 100 + h] = f2b(v);
    }
}

// ---------------- FC2 via bf16 MFMA (unchanged from round 2) ----------------
__global__ __launch_bounds__(256, 2) void fc2_mfma(
    const ushort* __restrict__ Xb, const ushort* __restrict__ W1b,
    const float* __restrict__ b1, const ushort* __restrict__ W2b,
    float* __restrict__ partial, int B) {
    __shared__ ushort sW1[64 * 192];
    __shared__ ushort sHid[4][64 * 56];
    const int tid = threadIdx.x;
    const int w = tid >> 6, l = tid & 63;
    const int lr = l & 15, lk = l >> 4;
    const int bid = blockIdx.x;
    const int mt = bid >> 2, split = bid & 3;
    const int m0 = mt * 64;
    const int u0 = (57 * split) / 4, u1 = (57 * (split + 1)) / 4;

    bf8 A[4][6];
    {
        const ushort* xp = Xb + (size_t)(m0 + lr) * 192 + lk * 8;
        #pragma unroll
        for (int mi = 0; mi < 4; ++mi)
            #pragma unroll
            for (int ks = 0; ks < 6; ++ks)
                A[mi][ks] = *(const bf8*)(xp + (size_t)mi * 16 * 192 + ks * 32);
    }

    f32x4 acc2[4][6];
    #pragma unroll
    for (int mi = 0; mi < 4; ++mi)
        #pragma unroll
        for (int nj = 0; nj < 6; ++nj) acc2[mi][nj] = (f32x4){0.f, 0.f, 0.f, 0.f};

    ushort* myHid = &sHid[w][0];
    const int nloc = w * 16 + lr;

    for (int u = u0; u < u1; ++u) {
        const int n0 = u * 128;
        #pragma unroll
        for (int h = 0; h < 2; ++h) {
            __syncthreads();
            #pragma unroll
            for (int p = 0; p < 6; ++p) {
                const ushort* g = W1b + (size_t)(n0 + h * 64) * 192 + (p * 4 + w) * 512 + l * 8;
                __builtin_amdgcn_global_load_lds(
                    (const __attribute__((address_space(1))) unsigned int*)g,
                    (__attribute__((address_space(3))) unsigned int*)(sW1 + (p * 4 + w) * 512),
                    16, 0, 0);
            }
            asm volatile("s_waitcnt vmcnt(0)" ::: "memory");
            __syncthreads();

            f32x4 acc1[4];
            #pragma unroll
            for (int mi = 0; mi < 4; ++mi) acc1[mi] = (f32x4){0.f, 0.f, 0.f, 0.f};
            #pragma unroll
            for (int ks = 0; ks < 6; ++ks) {
                int cs = ks * 4 + lk;
                int p = cs ^ (nloc & 7);
                bf8 Bf = *(const bf8*)(sW1 + nloc * 192 + p * 8);
                #pragma unroll
                for (int mi = 0; mi < 4; ++mi)
                    acc1[mi] = __builtin_amdgcn_mfma_f32_16x16x32_bf16(A[mi][ks], Bf, acc1[mi], 0, 0, 0);
            }
            int gn = n0 + h * 64 + nloc;
            float bias = (gn < 7240) ? b1[gn] : 0.f;
            #pragma unroll
            for (int mi = 0; mi < 4; ++mi)
                #pragma unroll
                for (int q = 0; q < 4; ++q) {
                    float v = fmaxf(acc1[mi][q] + bias, 0.f);
                    myHid[(mi * 16 + lk * 4 + q) * 56 + h * 16 + lr] = f2b(v);
                }
        }
        bf8 aF[4];
        #pragma unroll
        for (int mi = 0; mi < 4; ++mi)
            aF[mi] = *(const bf8*)(myHid + (mi * 16 + lr) * 56 + lk * 8);
        const size_t kbase = (size_t)n0 + (lk >> 1) * 64 + w * 16 + (lk & 1) * 8;
        #pragma unroll
        for (int nj = 0; nj < 6; ++nj) {
            bf8 Bf2 = *(const bf8*)(W2b + (size_t)(nj * 16 + lr) * 7296 + kbase);
            #pragma unroll
            for (int mi = 0; mi < 4; ++mi)
                acc2[mi][nj] = __builtin_amdgcn_mfma_f32_16x16x32_bf16(aF[mi], Bf2, acc2[mi][nj], 0, 0, 0);
        }
    }

    float* red1 = (float*)sW1;
    float* red2 = (float*)&sHid[0][0];
    __syncthreads();
    if (w == 1 || w == 3) {
        float* r_ = (w == 1) ? red1 : red2;
        #pragma unroll
        for (int mi = 0; mi < 4; ++mi)
            #pragma unroll
            for (int nj = 0; nj < 6; ++nj)
                #pragma unroll
                for (int q = 0; q < 4; ++q)
                    r_[(mi * 16 + lk * 4 + q) * 96 + nj * 16 + lr] = acc2[mi][nj][q];
    }
    __syncthreads();
    if (w == 0 || w == 2) {
        float* r_ = (w == 0) ? red1 : red2;
        #pragma unroll
        for (int mi = 0; mi < 4; ++mi)
            #pragma unroll
            for (int nj = 0; nj < 6; ++nj)
                #pragma unroll
                for (int q = 0; q < 4; ++q)
                    r_[(mi * 16 + lk * 4 + q) * 96 + nj * 16 + lr] += acc2[mi][nj][q];
    }
    __syncthreads();
    float* dst = partial + ((size_t)split * B + m0) * 96;
    for (int i = tid; i < 64 * 96; i += 256) dst[i] = red1[i] + red2[i];
}

// ---------------- fused tail: combine partials + FC3 + FC4 ----------------
__global__ __launch_bounds__(256) void tail_fused(
    const float* __restrict__ partial, const float* __restrict__ b2,
    const float* __restrict__ o_hS, const float* __restrict__ hSig_g,
    const float* __restrict__ wpad, const float* __restrict__ fc3_b,
    const float* __restrict__ fc4_W, const float* __restrict__ fc4_b,
    float* __restrict__ o_kg, float* __restrict__ o_hSn, int B) {
    __shared__ __align__(16) float sm[16 * 172 + 16 * 200];   // sIn3 | sIn4
    float* sIn3 = sm;
    float* sIn4 = sm + 16 * 172;
    const int tid = threadIdx.x;
    const int row0 = blockIdx.x * 16;

    for (int i = tid; i < 16 * 172 + 16 * 200; i += 256) sm[i] = 0.f;
    __syncthreads();
    // combine FC2 partials -> out2 -> o_kg + sIn3[81..170]
    for (int i = tid; i < 16 * 90; i += 256) {
        int r = i / 90, n = i - r * 90;
        size_t rowi = (size_t)(row0 + r);
        float v = partial[(rowi) * 96 + n] + partial[((size_t)B + rowi) * 96 + n]
                + partial[((size_t)2 * B + rowi) * 96 + n] + partial[((size_t)3 * B + rowi) * 96 + n]
                + b2[n];
        o_kg[rowi * 90 + n] = v;
        sIn3[r * 172 + 81 + n] = v;
    }
    // stage hS -> sIn3[0..80], hSigma -> sIn4[0..99]
    for (int i = tid; i < 16 * 81; i += 256) {
        int r = i / 81, n = i - r * 81;
        sIn3[r * 172 + n] = o_hS[(size_t)(row0 + r) * 81 + n];
    }
    for (int i = tid; i < 16 * 100; i += 256) {
        int r = i / 100, n = i - r * 100;
        sIn4[r * 200 + n] = hSig_g[(size_t)(row0 + r) * 100 + n];
    }
    __syncthreads();
    // FC3 -> sIn4[100..199] (relu)
    gemm_tile(sIn3, 172, 172, wpad + 125688, fc3_b, 100, 1, sIn4, 200, 100, nullptr, 0, 0, 0, tid);
    __syncthreads();
    // FC4 -> o_hSn (relu)
    gemm_tile(sIn4, 200, 200, fc4_W, fc4_b, 100, 1, nullptr, 0, 0, o_hSn, 100, 0, row0, tid);
}

extern "C" void kernel_launch(void* const* d_in, const int* in_sizes, int n_in,
                              void* d_out, int out_size, void* d_ws, size_t ws_size,
                              hipStream_t stream) {
    const float* obs_diff  = (const float*)d_in[0];
    const float* obs_innov = (const float*)d_in[1];
    const float* fw_evol   = (const float*)d_in[2];
    const float* fw_upd    = (const float*)d_in[3];
    const float* Q_Wih  = (const float*)d_in[4];
    const float* Q_Whh  = (const float*)d_in[5];
    const float* Q_bih  = (const float*)d_in[6];
    const float* Q_bhh  = (const float*)d_in[7];
    const float* Sig_Wih = (const float*)d_in[8];
    const float* Sig_bih = (const float*)d_in[10];
    const float* Sig_bhh = (const float*)d_in[11];
    const float* S_Wih  = (const float*)d_in[12];
    const float* S_Whh  = (const float*)d_in[13];
    const float* S_bih  = (const float*)d_in[14];
    const float* S_bhh  = (const float*)d_in[15];
    const float* R_Wih  = (const float*)d_in[16];
    const float* R_Whh  = (const float*)d_in[17];
    const float* R_bih  = (const float*)d_in[18];
    const float* R_bhh  = (const float*)d_in[19];
    const float* fc1_W = (const float*)d_in[20];
    const float* fc1_b = (const float*)d_in[21];
    const float* fc2_W1 = (const float*)d_in[22];
    const float* fc2_b1 = (const float*)d_in[23];
    const float* fc2_W2 = (const float*)d_in[24];
    const float* fc2_b2 = (const float*)d_in[25];
    const float* fc3_W = (const float*)d_in[26];
    const float* fc3_b = (const float*)d_in[27];
    const float* fc4_W = (const float*)d_in[28];
    const float* fc4_b = (const float*)d_in[29];
    const float* fc5_W = (const float*)d_in[30];
    const float* fc5_b = (const float*)d_in[31];
    const float* fc6_W = (const float*)d_in[32];
    const float* fc6_b = (const float*)d_in[33];
    const float* fc7_W = (const float*)d_in[34];
    const float* fc7_b = (const float*)d_in[35];
    const float* fc8_W = (const float*)d_in[36];
    const float* fc8_b = (const float*)d_in[37];

    const int B = in_sizes[0] / MD;   // 8192
    float* ws = (float*)d_ws;
    float* gh = ws;
    size_t off = 1024;
    float* wpad = ws + off; off += 143360;                     // padded small weights
    float* hSig_g = ws + off; off += (size_t)B * 100;
    ushort* Xb   = (ushort*)(ws + off); off += (size_t)B * 96; // [B][192] bf16
    ushort* W1b  = (ushort*)(ws + off); off += 700416;
    ushort* W2b  = (ushort*)(ws + off); off += 350208;
    float* part  = ws + off; off += (size_t)4 * B * 96;

    float* out = (float*)d_out;
    float* o_kg  = out;
    float* o_hS  = out + (size_t)B * 90;
    float* o_hSn = out + (size_t)B * 171;
    float* o_hQ  = out + (size_t)B * 271;
    float* o_hR  = out + (size_t)B * 371;

    hipLaunchKernelGGL(gh_precompute, dim3(1), dim3(512), 0, stream,
                       Q_Whh, Q_bhh, R_Whh, R_bhh, S_Whh, S_bhh, gh);
    hipLaunchKernelGGL(prep_weights, dim3((WPAD_TOTAL + 255) / 256), dim3(256), 0, stream,
                       fc5_W, fc6_W, fc7_W, fc8_W, Q_Wih, Sig_Wih, R_Wih, S_Wih, fc3_W, wpad);
    hipLaunchKernelGGL(convert_w1, dim3((7296 * 24 + 255) / 256), dim3(256), 0, stream, fc2_W1, W1b);
    hipLaunchKernelGGL(convert_w2, dim3((96 * 912 + 255) / 256), dim3(256), 0, stream, fc2_W2, W2b);
    hipLaunchKernelGGL(chain_fused, dim3(B / 16), dim3(256), 0, stream,
                       obs_diff, obs_innov, fw_evol, fw_upd,
                       wpad, gh, Q_bih, Sig_bih, Sig_bhh, R_bih, S_bih,
                       fc1_W, fc1_b, fc5_b, fc6_b, fc7_b, fc8_b,
                       o_hQ, o_hR, o_hS, hSig_g, Xb);
    hipLaunchKernelGGL(fc2_mfma, dim3((B / 64) * 4), dim3(256), 0, stream,
                       Xb, W1b, fc2_b1, W2b, part, B);
    hipLaunchKernelGGL(tail_fused, dim3(B / 16), dim3(256), 0, stream,
                       part, fc2_b2, o_hS, hSig_g, wpad, fc3_b, fc4_W, fc4_b,
                       o_kg, o_hSn, B);
}

// Round 4
// 135.314 us; speedup vs baseline: 17.1670x; 1.7234x over previous
//
#include <hip/hip_runtime.h>
#include <math.h>

#define SD 10
#define MD 9

typedef short bf8 __attribute__((ext_vector_type(8)));
typedef float f32x4 __attribute__((ext_vector_type(4)));

__device__ inline ushort f2b(float f) {
    union { float f; unsigned u; } v; v.f = f;
    unsigned r = v.u + 0x7FFF + ((v.u >> 16) & 1);
    return (ushort)(r >> 16);
}

// ---------------- constant gh precompute (h0 is batch-constant) ----------------
__global__ void gh_precompute(const float* __restrict__ Q_Whh, const float* __restrict__ Q_bhh,
                              const float* __restrict__ R_Whh, const float* __restrict__ R_bhh,
                              const float* __restrict__ S_Whh, const float* __restrict__ S_bhh,
                              float* __restrict__ gh) {
    int j = threadIdx.x;
    if (j < 300) {
        float s = Q_bhh[j];
        #pragma unroll
        for (int i = 0; i < 10; ++i) s += Q_Whh[j * 100 + 11 * i];
        gh[j] = s;
    }
    if (j < 243) {
        float s = R_bhh[j];
        #pragma unroll
        for (int i = 0; i < 9; ++i) s += R_Whh[j * 81 + 10 * i];
        gh[320 + j] = s;
        float s2 = S_bhh[j];
        #pragma unroll
        for (int i = 0; i < 9; ++i) s2 += S_Whh[j * 81 + 10 * i];
        gh[576 + j] = s2;
    }
}

// ---------------- all small weights -> bf16 zero-padded [Npad][Kpad] ----------------
// seg: 0 fc5[64][32]@0  1 fc6[64][32]@2048  2 fc7[48][32]@4096  3 fc8[48][32]@5632
//      4 Q[304][64]@7168  5 Sig[304][160]@26624  6 R[256][64]@75264  7 S[256][224]@91648
//      8 fc1[96][128]@148992  9 fc3[112][192]@161280  10 fc4[112][224]@182784  total 207872
#define WBF_TOTAL 207872
#define W5O 0
#define W6O 2048
#define W7O 4096
#define W8O 5632
#define WQO 7168
#define WSIGO 26624
#define WRO 75264
#define WSO 91648
#define WFC1O 148992
#define WFC3O 161280
#define WFC4O 182784
__global__ void prep_wbf(const float* __restrict__ w5, const float* __restrict__ w6,
                         const float* __restrict__ w7, const float* __restrict__ w8,
                         const float* __restrict__ wq, const float* __restrict__ wsig,
                         const float* __restrict__ wr, const float* __restrict__ wss,
                         const float* __restrict__ w1, const float* __restrict__ w3,
                         const float* __restrict__ w4, ushort* __restrict__ dst) {
    int idx = blockIdx.x * 256 + threadIdx.x;
    if (idx >= WBF_TOTAL) return;
    const int offs[12] = {W5O, W6O, W7O, W8O, WQO, WSIGO, WRO, WSO, WFC1O, WFC3O, WFC4O, WBF_TOTAL};
    const int Ns[11]  = {50, 50, 45, 45, 300, 300, 243, 243, 81, 100, 100};
    const int Ks[11]  = {10, 10, 9, 9, 50, 150, 45, 207, 100, 171, 200};
    const int KPs[11] = {32, 32, 32, 32, 64, 160, 64, 224, 128, 192, 224};
    const float* srcs[11] = {w5, w6, w7, w8, wq, wsig, wr, wss, w1, w3, w4};
    int s = 0;
    for (int i = 1; i < 11; ++i) if (idx >= offs[i]) s = i;
    int loc = idx - offs[s];
    int r = loc / KPs[s], k = loc - r * KPs[s];
    float v = (r < Ns[s] && k < Ks[s]) ? srcs[s][(size_t)r * Ks[s] + k] : 0.f;
    dst[idx] = f2b(v);
}

// ---------------- weight converts for FC2 MFMA (unchanged) ----------------
__global__ void convert_w1(const float* __restrict__ W1, ushort* __restrict__ W1b) {
    int idx = blockIdx.x * 256 + threadIdx.x;
    if (idx >= 7296 * 24) return;
    int r = idx / 24, p = idx - r * 24;
    int cs = p ^ (r & 7);
    union { ushort u[8]; uint4 v; } o;
    #pragma unroll
    for (int j = 0; j < 8; ++j) {
        int k = cs * 8 + j;
        float val = (r < 7240 && k < 181) ? W1[(size_t)r * 181 + k] : 0.f;
        o.u[j] = f2b(val);
    }
    *(uint4*)(W1b + (size_t)r * 192 + p * 8) = o.v;
}

__global__ void convert_w2(const float* __restrict__ W2, ushort* __restrict__ W2b) {
    int idx = blockIdx.x * 256 + threadIdx.x;
    if (idx >= 96 * 912) return;
    int r = idx / 912, p = idx - r * 912;
    union { ushort u[8]; uint4 v; } o;
    #pragma unroll
    for (int j = 0; j < 8; ++j) {
        int k = p * 8 + j;
        float val = (r < 90 && k < 7240) ? W2[(size_t)r * 7240 + k] : 0.f;
        o.u[j] = f2b(val);
    }
    *(uint4*)(W2b + (size_t)r * 7296 + p * 8) = o.v;
}

// ---------------- generic MFMA layer: 16 rows x Npad cols, waves split N-tiles ----------------
// MODE 0: sGi[m*ldg + n] = acc + bias   (f32, for GRU gates)
// MODE 1: sDst[m*strideD + dcol + n] = bf16(relu(acc + bias))
// MODE 2: gDst[(row0+m)*gld + n] = relu(acc + bias)  (f32 global)
template <int KSTEPS, int MODE>
__device__ __forceinline__ void mfma_layer(
    const ushort* sX, int strideX,
    const ushort* __restrict__ Wb, int Kpad, int ntiles,
    const float* __restrict__ bias, int N,
    int w, int lr, int lk,
    float* sGi, int ldg,
    ushort* sDst, int strideD, int dcol,
    float* gDst, int gld, int row0) {
    bf8 a[KSTEPS];
    #pragma unroll
    for (int ks = 0; ks < KSTEPS; ++ks)
        a[ks] = *(const bf8*)(sX + lr * strideX + ks * 32 + lk * 8);
    for (int nt = w; nt < ntiles; nt += 4) {
        f32x4 acc = (f32x4){0.f, 0.f, 0.f, 0.f};
        #pragma unroll
        for (int ks = 0; ks < KSTEPS; ++ks) {
            bf8 Bf = *(const bf8*)(Wb + (size_t)(nt * 16 + lr) * Kpad + ks * 32 + lk * 8);
            acc = __builtin_amdgcn_mfma_f32_16x16x32_bf16(a[ks], Bf, acc, 0, 0, 0);
        }
        int n = nt * 16 + lr;
        if (n < N) {
            float b = bias[n];
            #pragma unroll
            for (int q = 0; q < 4; ++q) {
                float v = acc[q] + b;
                int m = lk * 4 + q;
                if (MODE == 0) {
                    sGi[m * ldg + n] = v;
                } else if (MODE == 1) {
                    v = fmaxf(v, 0.f);
                    sDst[m * strideD + dcol + n] = f2b(v);
                } else {
                    v = fmaxf(v, 0.f);
                    gDst[(size_t)(row0 + m) * gld + n] = v;
                }
            }
        }
    }
}

// ---------------- fused chain via MFMA: FC5-8, GRU_Q/Sigma/R/S, FC1 ----------------
// bf16 LDS staging regions (ushort offsets); strides chosen 16B-aligned & <=2-way bank aliased
#define U_NORM  0      // [16][136]: fwu@0, fwe@32, obs@64, obsi@96 (Kpad 32 each)
#define U_OUT5  2176   // [16][72]  Kpad 64
#define U_INSIG 3328   // [16][168] Kpad 160  (hQ@0..99 | FC6@100..149)
#define U_OUT8  6016   // [16][72]  Kpad 64
#define U_INS   7168   // [16][232] Kpad 224  (FC1@0..80 | FC7@81..125 | hR@126..206)
#define U_HSIG  10880  // [16][136] Kpad 128
#define U_TOT   13056
__global__ __launch_bounds__(256) void chain_mfma(
    const float* __restrict__ obs_diff, const float* __restrict__ obs_innov,
    const float* __restrict__ fw_evol, const float* __restrict__ fw_upd,
    const ushort* __restrict__ wbf, const float* __restrict__ gh,
    const float* __restrict__ Q_bih, const float* __restrict__ Sig_bih,
    const float* __restrict__ Sig_bhh,
    const float* __restrict__ R_bih, const float* __restrict__ S_bih,
    const float* __restrict__ fc1_b, const float* __restrict__ fc5_b,
    const float* __restrict__ fc6_b, const float* __restrict__ fc7_b,
    const float* __restrict__ fc8_b,
    float* __restrict__ o_hQ, float* __restrict__ o_hR, float* __restrict__ o_hS,
    float* __restrict__ hSig_g, ushort* __restrict__ Xb) {
    __shared__ __align__(16) ushort su[U_TOT];
    __shared__ __align__(16) float sGi[16 * 305];
    const int tid = threadIdx.x;
    const int w = tid >> 6, l = tid & 63, lr = l & 15, lk = l >> 4;
    const int row0 = blockIdx.x * 16;

    for (int i = tid; i < U_TOT; i += 256) su[i] = 0;
    __syncthreads();
    // load + L2-normalize the 4 raw inputs -> bf16
    if (tid < 64) {
        int v = tid >> 4, r = tid & 15;
        const float* src = (v == 0) ? fw_upd : (v == 1) ? fw_evol : (v == 2) ? obs_diff : obs_innov;
        int len = (v < 2) ? 10 : 9;
        float x[10]; float s = 0.f;
        for (int k = 0; k < len; ++k) { x[k] = src[(size_t)(row0 + r) * len + k]; s += x[k] * x[k]; }
        float sc = 1.f / fmaxf(sqrtf(s), 1e-12f);
        for (int k = 0; k < len; ++k) su[U_NORM + r * 136 + v * 32 + k] = f2b(x[k] * sc);
    }
    __syncthreads();
    // FC5 -> out5, FC6 -> inSig[100..], FC7 -> inS[81..], FC8 -> out8
    mfma_layer<1, 1>(su + U_NORM + 0, 136, wbf + W5O, 32, 4, fc5_b, 50, w, lr, lk,
                     nullptr, 0, su + U_OUT5, 72, 0, nullptr, 0, 0);
    mfma_layer<1, 1>(su + U_NORM + 32, 136, wbf + W6O, 32, 4, fc6_b, 50, w, lr, lk,
                     nullptr, 0, su + U_INSIG, 168, 100, nullptr, 0, 0);
    mfma_layer<1, 1>(su + U_NORM + 64, 136, wbf + W7O, 32, 3, fc7_b, 45, w, lr, lk,
                     nullptr, 0, su + U_INS, 232, 81, nullptr, 0, 0);
    mfma_layer<1, 1>(su + U_NORM + 96, 136, wbf + W8O, 32, 3, fc8_b, 45, w, lr, lk,
                     nullptr, 0, su + U_OUT8, 72, 0, nullptr, 0, 0);
    __syncthreads();
    // GRU_Q gi
    mfma_layer<2, 0>(su + U_OUT5, 72, wbf + WQO, 64, 19, Q_bih, 300, w, lr, lk,
                     sGi, 305, nullptr, 0, 0, nullptr, 0, 0);
    __syncthreads();
    // Q gates -> inSig[0..99] bf16 + o_hQ
    for (int i = tid; i < 16 * 100; i += 256) {
        int r = i / 100, h = i - r * 100;
        float ir = sGi[r * 305 + h], iz = sGi[r * 305 + 100 + h], in = sGi[r * 305 + 200 + h];
        float rr = 1.f / (1.f + __expf(-(ir + gh[h])));
        float zz = 1.f / (1.f + __expf(-(iz + gh[100 + h])));
        float t = in + rr * gh[200 + h];
        float nn = 1.f - 2.f / (1.f + __expf(2.f * t));
        float h0 = ((h % 11) == 0) ? 1.f : 0.f;
        float v = (1.f - zz) * nn + zz * h0;
        su[U_INSIG + r * 168 + h] = f2b(v);
        o_hQ[(size_t)(row0 + r) * 100 + h] = v;
    }
    __syncthreads();
    // GRU_Sigma gi
    mfma_layer<5, 0>(su + U_INSIG, 168, wbf + WSIGO, 160, 19, Sig_bih, 300, w, lr, lk,
                     sGi, 305, nullptr, 0, 0, nullptr, 0, 0);
    __syncthreads();
    // Sigma gates -> hSig LDS bf16 + hSig_g f32 + Xb[0..99]
    for (int i = tid; i < 16 * 100; i += 256) {
        int r = i / 100, h = i - r * 100;
        float ir = sGi[r * 305 + h], iz = sGi[r * 305 + 100 + h], in = sGi[r * 305 + 200 + h];
        float rr = 1.f / (1.f + __expf(-(ir + Sig_bhh[h])));
        float zz = 1.f / (1.f + __expf(-(iz + Sig_bhh[100 + h])));
        float t = in + rr * Sig_bhh[200 + h];
        float nn = 1.f - 2.f / (1.f + __expf(2.f * t));
        float v = (1.f - zz) * nn;
        su[U_HSIG + r * 136 + h] = f2b(v);
        hSig_g[(size_t)(row0 + r) * 100 + h] = v;
        Xb[(size_t)(row0 + r) * 192 + h] = f2b(v);
    }
    __syncthreads();
    // FC1(hSigma) -> inS[0..80] ; GRU_R gi (independent dests, one barrier after)
    mfma_layer<4, 1>(su + U_HSIG, 136, wbf + WFC1O, 128, 6, fc1_b, 81, w, lr, lk,
                     nullptr, 0, su + U_INS, 232, 0, nullptr, 0, 0);
    mfma_layer<2, 0>(su + U_OUT8, 72, wbf + WRO, 64, 16, R_bih, 243, w, lr, lk,
                     sGi, 305, nullptr, 0, 0, nullptr, 0, 0);
    __syncthreads();
    // R gates -> inS[126..206] bf16 + o_hR
    for (int i = tid; i < 16 * 81; i += 256) {
        int r = i / 81, h = i - r * 81;
        float ir = sGi[r * 305 + h], iz = sGi[r * 305 + 81 + h], in = sGi[r * 305 + 162 + h];
        float rr = 1.f / (1.f + __expf(-(ir + gh[320 + h])));
        float zz = 1.f / (1.f + __expf(-(iz + gh[320 + 81 + h])));
        float t = in + rr * gh[320 + 162 + h];
        float nn = 1.f - 2.f / (1.f + __expf(2.f * t));
        float h0 = ((h % 10) == 0) ? 1.f : 0.f;
        float v = (1.f - zz) * nn + zz * h0;
        su[U_INS + r * 232 + 126 + h] = f2b(v);
        o_hR[(size_t)(row0 + r) * 81 + h] = v;
    }
    __syncthreads();
    // GRU_S gi
    mfma_layer<7, 0>(su + U_INS, 232, wbf + WSO, 224, 16, S_bih, 243, w, lr, lk,
                     sGi, 305, nullptr, 0, 0, nullptr, 0, 0);
    __syncthreads();
    // S gates -> o_hS + Xb[100..180]
    for (int i = tid; i < 16 * 81; i += 256) {
        int r = i / 81, h = i - r * 81;
        float ir = sGi[r * 305 + h], iz = sGi[r * 305 + 81 + h], in = sGi[r * 305 + 162 + h];
        float rr = 1.f / (1.f + __expf(-(ir + gh[576 + h])));
        float zz = 1.f / (1.f + __expf(-(iz + gh[576 + 81 + h])));
        float t = in + rr * gh[576 + 162 + h];
        float nn = 1.f - 2.f / (1.f + __expf(2.f * t));
        float h0 = ((h % 10) == 0) ? 1.f : 0.f;
        float v = (1.f - zz) * nn + zz * h0;
        o_hS[(size_t)(row0 + r) * 81 + h] = v;
        Xb[(size_t)(row0 + r) * 192 + 100 + h] = f2b(v);
    }
}

// ---------------- FC2 via bf16 MFMA (unchanged) ----------------
__global__ __launch_bounds__(256, 2) void fc2_mfma(
    const ushort* __restrict__ Xb, const ushort* __restrict__ W1b,
    const float* __restrict__ b1, const ushort* __restrict__ W2b,
    float* __restrict__ partial, int B) {
    __shared__ ushort sW1[64 * 192];
    __shared__ ushort sHid[4][64 * 56];
    const int tid = threadIdx.x;
    const int w = tid >> 6, l = tid & 63;
    const int lr = l & 15, lk = l >> 4;
    const int bid = blockIdx.x;
    const int mt = bid >> 2, split = bid & 3;
    const int m0 = mt * 64;
    const int u0 = (57 * split) / 4, u1 = (57 * (split + 1)) / 4;

    bf8 A[4][6];
    {
        const ushort* xp = Xb + (size_t)(m0 + lr) * 192 + lk * 8;
        #pragma unroll
        for (int mi = 0; mi < 4; ++mi)
            #pragma unroll
            for (int ks = 0; ks < 6; ++ks)
                A[mi][ks] = *(const bf8*)(xp + (size_t)mi * 16 * 192 + ks * 32);
    }

    f32x4 acc2[4][6];
    #pragma unroll
    for (int mi = 0; mi < 4; ++mi)
        #pragma unroll
        for (int nj = 0; nj < 6; ++nj) acc2[mi][nj] = (f32x4){0.f, 0.f, 0.f, 0.f};

    ushort* myHid = &sHid[w][0];
    const int nloc = w * 16 + lr;

    for (int u = u0; u < u1; ++u) {
        const int n0 = u * 128;
        #pragma unroll
        for (int h = 0; h < 2; ++h) {
            __syncthreads();
            #pragma unroll
            for (int p = 0; p < 6; ++p) {
                const ushort* g = W1b + (size_t)(n0 + h * 64) * 192 + (p * 4 + w) * 512 + l * 8;
                __builtin_amdgcn_global_load_lds(
                    (const __attribute__((address_space(1))) unsigned int*)g,
                    (__attribute__((address_space(3))) unsigned int*)(sW1 + (p * 4 + w) * 512),
                    16, 0, 0);
            }
            asm volatile("s_waitcnt vmcnt(0)" ::: "memory");
            __syncthreads();

            f32x4 acc1[4];
            #pragma unroll
            for (int mi = 0; mi < 4; ++mi) acc1[mi] = (f32x4){0.f, 0.f, 0.f, 0.f};
            #pragma unroll
            for (int ks = 0; ks < 6; ++ks) {
                int cs = ks * 4 + lk;
                int p = cs ^ (nloc & 7);
                bf8 Bf = *(const bf8*)(sW1 + nloc * 192 + p * 8);
                #pragma unroll
                for (int mi = 0; mi < 4; ++mi)
                    acc1[mi] = __builtin_amdgcn_mfma_f32_16x16x32_bf16(A[mi][ks], Bf, acc1[mi], 0, 0, 0);
            }
            int gn = n0 + h * 64 + nloc;
            float bias = (gn < 7240) ? b1[gn] : 0.f;
            #pragma unroll
            for (int mi = 0; mi < 4; ++mi)
                #pragma unroll
                for (int q = 0; q < 4; ++q) {
                    float v = fmaxf(acc1[mi][q] + bias, 0.f);
                    myHid[(mi * 16 + lk * 4 + q) * 56 + h * 16 + lr] = f2b(v);
                }
        }
        bf8 aF[4];
        #pragma unroll
        for (int mi = 0; mi < 4; ++mi)
            aF[mi] = *(const bf8*)(myHid + (mi * 16 + lr) * 56 + lk * 8);
        const size_t kbase = (size_t)n0 + (lk >> 1) * 64 + w * 16 + (lk & 1) * 8;
        #pragma unroll
        for (int nj = 0; nj < 6; ++nj) {
            bf8 Bf2 = *(const bf8*)(W2b + (size_t)(nj * 16 + lr) * 7296 + kbase);
            #pragma unroll
            for (int mi = 0; mi < 4; ++mi)
                acc2[mi][nj] = __builtin_amdgcn_mfma_f32_16x16x32_bf16(aF[mi], Bf2, acc2[mi][nj], 0, 0, 0);
        }
    }

    float* red1 = (float*)sW1;
    float* red2 = (float*)&sHid[0][0];
    __syncthreads();
    if (w == 1 || w == 3) {
        float* r_ = (w == 1) ? red1 : red2;
        #pragma unroll
        for (int mi = 0; mi < 4; ++mi)
            #pragma unroll
            for (int nj = 0; nj < 6; ++nj)
                #pragma unroll
                for (int q = 0; q < 4; ++q)
                    r_[(mi * 16 + lk * 4 + q) * 96 + nj * 16 + lr] = acc2[mi][nj][q];
    }
    __syncthreads();
    if (w == 0 || w == 2) {
        float* r_ = (w == 0) ? red1 : red2;
        #pragma unroll
        for (int mi = 0; mi < 4; ++mi)
            #pragma unroll
            for (int nj = 0; nj < 6; ++nj)
                #pragma unroll
                for (int q = 0; q < 4; ++q)
                    r_[(mi * 16 + lk * 4 + q) * 96 + nj * 16 + lr] += acc2[mi][nj][q];
    }
    __syncthreads();
    float* dst = partial + ((size_t)split * B + m0) * 96;
    for (int i = tid; i < 64 * 96; i += 256) dst[i] = red1[i] + red2[i];
}

// ---------------- fused tail: combine partials + FC3 + FC4 via MFMA ----------------
__global__ __launch_bounds__(256) void tail_mfma(
    const float* __restrict__ partial, const float* __restrict__ b2,
    const float* __restrict__ o_hS, const float* __restrict__ hSig_g,
    const ushort* __restrict__ wbf, const float* __restrict__ fc3_b,
    const float* __restrict__ fc4_b,
    float* __restrict__ o_kg, float* __restrict__ o_hSn, int B) {
    __shared__ __align__(16) ushort s3[16 * 200];   // [hS 0..80 | KG 81..170 | pad] Kpad 192
    __shared__ __align__(16) ushort s4[16 * 232];   // [hSig 0..99 | FC3 100..199 | pad] Kpad 224
    const int tid = threadIdx.x;
    const int w = tid >> 6, l = tid & 63, lr = l & 15, lk = l >> 4;
    const int row0 = blockIdx.x * 16;

    for (int i = tid; i < 16 * 200; i += 256) s3[i] = 0;
    for (int i = tid; i < 16 * 232; i += 256) s4[i] = 0;
    __syncthreads();
    for (int i = tid; i < 16 * 81; i += 256) {
        int r = i / 81, n = i - r * 81;
        s3[r * 200 + n] = f2b(o_hS[(size_t)(row0 + r) * 81 + n]);
    }
    for (int i = tid; i < 16 * 100; i += 256) {
        int r = i / 100, n = i - r * 100;
        s4[r * 232 + n] = f2b(hSig_g[(size_t)(row0 + r) * 100 + n]);
    }
    for (int i = tid; i < 16 * 90; i += 256) {
        int r = i / 90, n = i - r * 90;
        size_t rw = (size_t)(row0 + r);
        float v = partial[rw * 96 + n] + partial[((size_t)B + rw) * 96 + n]
                + partial[((size_t)2 * B + rw) * 96 + n] + partial[((size_t)3 * B + rw) * 96 + n]
                + b2[n];
        o_kg[rw * 90 + n] = v;
        s3[r * 200 + 81 + n] = f2b(v);
    }
    __syncthreads();
    // FC3 -> s4 cols 100..199 (relu, bf16)
    mfma_layer<6, 1>(s3, 200, wbf + WFC3O, 192, 7, fc3_b, 100, w, lr, lk,
                     nullptr, 0, s4, 232, 100, nullptr, 0, 0);
    __syncthreads();
    // FC4 -> o_hSn (relu, f32 global)
    mfma_layer<7, 2>(s4, 232, wbf + WFC4O, 224, 7, fc4_b, 100, w, lr, lk,
                     nullptr, 0, nullptr, 0, 0, o_hSn, 100, row0);
}

extern "C" void kernel_launch(void* const* d_in, const int* in_sizes, int n_in,
                              void* d_out, int out_size, void* d_ws, size_t ws_size,
                              hipStream_t stream) {
    const float* obs_diff  = (const float*)d_in[0];
    const float* obs_innov = (const float*)d_in[1];
    const float* fw_evol   = (const float*)d_in[2];
    const float* fw_upd    = (const float*)d_in[3];
    const float* Q_Wih  = (const float*)d_in[4];
    const float* Q_Whh  = (const float*)d_in[5];
    const float* Q_bih  = (const float*)d_in[6];
    const float* Q_bhh  = (const float*)d_in[7];
    const float* Sig_Wih = (const float*)d_in[8];
    const float* Sig_bih = (const float*)d_in[10];
    const float* Sig_bhh = (const float*)d_in[11];
    const float* S_Wih  = (const float*)d_in[12];
    const float* S_Whh  = (const float*)d_in[13];
    const float* S_bih  = (const float*)d_in[14];
    const float* S_bhh  = (const float*)d_in[15];
    const float* R_Wih  = (const float*)d_in[16];
    const float* R_Whh  = (const float*)d_in[17];
    const float* R_bih  = (const float*)d_in[18];
    const float* R_bhh  = (const float*)d_in[19];
    const float* fc1_W = (const float*)d_in[20];
    const float* fc1_b = (const float*)d_in[21];
    const float* fc2_W1 = (const float*)d_in[22];
    const float* fc2_b1 = (const float*)d_in[23];
    const float* fc2_W2 = (const float*)d_in[24];
    const float* fc2_b2 = (const float*)d_in[25];
    const float* fc3_W = (const float*)d_in[26];
    const float* fc3_b = (const float*)d_in[27];
    const float* fc4_W = (const float*)d_in[28];
    const float* fc4_b = (const float*)d_in[29];
    const float* fc5_W = (const float*)d_in[30];
    const float* fc5_b = (const float*)d_in[31];
    const float* fc6_W = (const float*)d_in[32];
    const float* fc6_b = (const float*)d_in[33];
    const float* fc7_W = (const float*)d_in[34];
    const float* fc7_b = (const float*)d_in[35];
    const float* fc8_W = (const float*)d_in[36];
    const float* fc8_b = (const float*)d_in[37];

    const int B = in_sizes[0] / MD;   // 8192
    float* ws = (float*)d_ws;
    float* gh = ws;
    size_t off = 1024;
    ushort* wbf = (ushort*)(ws + off); off += WBF_TOTAL / 2;       // bf16 small weights
    float* hSig_g = ws + off; off += (size_t)B * 100;
    ushort* Xb   = (ushort*)(ws + off); off += (size_t)B * 96;     // [B][192] bf16
    ushort* W1b  = (ushort*)(ws + off); off += 700416;
    ushort* W2b  = (ushort*)(ws + off); off += 350208;
    float* part  = ws + off; off += (size_t)4 * B * 96;

    float* out = (float*)d_out;
    float* o_kg  = out;
    float* o_hS  = out + (size_t)B * 90;
    float* o_hSn = out + (size_t)B * 171;
    float* o_hQ  = out + (size_t)B * 271;
    float* o_hR  = out + (size_t)B * 371;

    hipLaunchKernelGGL(gh_precompute, dim3(1), dim3(512), 0, stream,
                       Q_Whh, Q_bhh, R_Whh, R_bhh, S_Whh, S_bhh, gh);
    hipLaunchKernelGGL(prep_wbf, dim3((WBF_TOTAL + 255) / 256), dim3(256), 0, stream,
                       fc5_W, fc6_W, fc7_W, fc8_W, Q_Wih, Sig_Wih, R_Wih, S_Wih,
                       fc1_W, fc3_W, fc4_W, wbf);
    hipLaunchKernelGGL(convert_w1, dim3((7296 * 24 + 255) / 256), dim3(256), 0, stream, fc2_W1, W1b);
    hipLaunchKernelGGL(convert_w2, dim3((96 * 912 + 255) / 256), dim3(256), 0, stream, fc2_W2, W2b);
    hipLaunchKernelGGL(chain_mfma, dim3(B / 16), dim3(256), 0, stream,
                       obs_diff, obs_innov, fw_evol, fw_upd,
                       wbf, gh, Q_bih, Sig_bih, Sig_bhh, R_bih, S_bih,
                       fc1_b, fc5_b, fc6_b, fc7_b, fc8_b,
                       o_hQ, o_hR, o_hS, hSig_g, Xb);
    hipLaunchKernelGGL(fc2_mfma, dim3((B / 64) * 4), dim3(256), 0, stream,
                       Xb, W1b, fc2_b1, W2b, part, B);
    hipLaunchKernelGGL(tail_mfma, dim3(B / 16), dim3(256), 0, stream,
                       part, fc2_b2, o_hS, hSig_g, wbf, fc3_b, fc4_b,
                       o_kg, o_hSn, B);
}